// Round 7
// baseline (445.159 us; speedup 1.0000x reference)
//
#include <hip/hip_runtime.h>

// MoE forward, MI355X. fp32 router/dispatch (exact top-k), bf16 MFMA grouped
// GEMMs (9 groups = 8 experts + shared), fp32-atomic scatter-combine.
// R6: 8-phase-style fine interleave (T3+T4 proper): BK=64, 3 LDS buffers,
// 4 phases per K-tile, each {ds_read frags || stage issue} -> bar -> 8 MFMA
// -> bar. vmcnt(6) once per K-tile (drain 6->0 at tail). sched_barrier(0)
// pins phase edges. Swizzle identical to R3-verified BK=64 mapping.

#define NTOK 8192
#define DDIM 1024
#define HDIM 1408
#define CAP  2560
#define NROWS (NTOK + 8*CAP)   // 28672 GEMM rows: [0,8192) shared, then 8*2560 expert slots
#define YN   8388608           // NTOK*DDIM

typedef __bf16 bf16x8 __attribute__((ext_vector_type(8)));
typedef float  f32x4  __attribute__((ext_vector_type(4)));

typedef __attribute__((address_space(1))) void gvoid_t;
typedef __attribute__((address_space(3))) void svoid_t;

static __device__ __forceinline__ void load_lds16(const void* g, void* l) {
  // 16B per lane, LDS dest = wave-uniform base + lane*16 (linear)
  __builtin_amdgcn_global_load_lds((gvoid_t*)g, (svoid_t*)l, 16, 0, 0);
}

#define BARS() do { __builtin_amdgcn_sched_barrier(0); \
                    __builtin_amdgcn_s_barrier();      \
                    __builtin_amdgcn_sched_barrier(0); } while (0)
#define MF(M, AV, N, BV) \
  acc[M][N] = __builtin_amdgcn_mfma_f32_16x16x32_bf16(AV, BV, acc[M][N], 0, 0, 0)
#define MF8(MA, MB)                                                        \
  __builtin_amdgcn_s_setprio(1);                                           \
  MF(MA, a0, 0, b0); MF(MA, a0, 1, b1); MF(MA, a0, 2, b2); MF(MA, a0, 3, b3); \
  MF(MB, a1, 0, b0); MF(MB, a1, 1, b1); MF(MB, a1, 2, b2); MF(MB, a1, 3, b3); \
  __builtin_amdgcn_s_setprio(0)

// ---------------- zero y + aux + accumulators ----------------
__global__ __launch_bounds__(256) void zero_kernel(float* __restrict__ y,
                                                   float* __restrict__ psum,
                                                   int* __restrict__ fcnt) {
  size_t idx = (size_t)blockIdx.x * 256 + threadIdx.x;
  float4 z = make_float4(0.f, 0.f, 0.f, 0.f);
  float4* p = (float4*)y;
#pragma unroll
  for (int j = 0; j < 4; ++j) p[idx + (size_t)j * 524288] = z;
  if (idx == 0) {
    y[YN] = 0.f;
    for (int e = 0; e < 8; ++e) { psum[e] = 0.f; fcnt[e] = 0; }
  }
}

// ---------------- fp32 -> bf16 (x) ----------------
__global__ __launch_bounds__(256) void convx_kernel(const float* __restrict__ in,
                                                    __bf16* __restrict__ out) {
  size_t i = ((size_t)blockIdx.x * 256 + threadIdx.x) * 8;
  float4 a = *(const float4*)(in + i);
  float4 b = *(const float4*)(in + i + 4);
  bf16x8 o;
  o[0] = (__bf16)a.x; o[1] = (__bf16)a.y; o[2] = (__bf16)a.z; o[3] = (__bf16)a.w;
  o[4] = (__bf16)b.x; o[5] = (__bf16)b.y; o[6] = (__bf16)b.z; o[7] = (__bf16)b.w;
  *(bf16x8*)(out + i) = o;
}

// ---------------- transpose + convert weights: in[R][C] f32 -> out[C][R] bf16 ----------------
__global__ __launch_bounds__(256) void tconv_kernel(const float* __restrict__ in,
                                                    __bf16* __restrict__ out, int R, int C) {
  __shared__ float t[32][33];
  size_t mo = (size_t)blockIdx.z * R * C;
  const float* ip = in + mo;
  __bf16* op = out + mo;
  int c0 = blockIdx.x * 32, r0 = blockIdx.y * 32;
  int tx = threadIdx.x, ty = threadIdx.y;  // block (32,8)
#pragma unroll
  for (int k2 = 0; k2 < 4; ++k2)
    t[ty + k2 * 8][tx] = ip[(size_t)(r0 + ty + k2 * 8) * C + c0 + tx];
  __syncthreads();
#pragma unroll
  for (int k2 = 0; k2 < 4; ++k2)
    op[(size_t)(c0 + ty + k2 * 8) * R + r0 + tx] = (__bf16)t[tx][ty + k2 * 8];
}

// ---------------- router: fp32 logits, softmax, top-2, renorm, aux stats ----------------
__global__ __launch_bounds__(256) void router_kernel(
    const float* __restrict__ x, const float* __restrict__ rw,
    int2* __restrict__ e01, float2* __restrict__ p01,
    int* __restrict__ tok_row, float* __restrict__ scale_row,
    float* __restrict__ psum, int* __restrict__ fcnt) {
  __shared__ float rwl[8 * 1024];
  __shared__ float ps[8];
  __shared__ int fc[8];
  int tid = threadIdx.x;
  if (tid < 8) { ps[tid] = 0.f; fc[tid] = 0; }
  float4* rl4 = (float4*)rwl;
  const float4* rg4 = (const float4*)rw;
#pragma unroll
  for (int j = 0; j < 8; ++j) rl4[tid + 256 * j] = rg4[tid + 256 * j];
  __syncthreads();
  int lane = tid & 63, wid = tid >> 6;
  for (int it = 0; it < 8; ++it) {
    int t = blockIdx.x * 32 + wid * 8 + it;
    const float4* xt = (const float4*)(x + (size_t)t * DDIM);
    float a[8];
#pragma unroll
    for (int e = 0; e < 8; ++e) a[e] = 0.f;
#pragma unroll
    for (int jj = 0; jj < 4; ++jj) {
      float4 v = xt[lane * 4 + jj];
#pragma unroll
      for (int e = 0; e < 8; ++e) {
        float4 w = rl4[e * 256 + lane * 4 + jj];
        a[e] += v.x * w.x + v.y * w.y + v.z * w.z + v.w * w.w;
      }
    }
#pragma unroll
    for (int off = 32; off >= 1; off >>= 1)
#pragma unroll
      for (int e = 0; e < 8; ++e) a[e] += __shfl_xor(a[e], off);
    if (lane == 0) {
      int am = 0; float m = a[0];
      for (int e = 1; e < 8; ++e) if (a[e] > m) { m = a[e]; am = e; }
      float s = 0.f, ex[8];
      for (int e = 0; e < 8; ++e) { ex[e] = expf(a[e] - m); s += ex[e]; }
      float inv = 1.f / s;
      int am2 = -1; float m2 = -3.4e38f;
      for (int e = 0; e < 8; ++e) if (e != am && a[e] > m2) { m2 = a[e]; am2 = e; }
      float p0 = ex[am] * inv, p1 = ex[am2] * inv;
      float rn = 1.f / (p0 + p1 + 1e-9f);
      e01[t] = make_int2(am, am2);
      p01[t] = make_float2(p0 * rn, p1 * rn);
      tok_row[t] = t;            // shared-group rows: identity gather, weight 1
      scale_row[t] = 1.f;
      atomicAdd(&fc[am], 1);
      for (int e = 0; e < 8; ++e) atomicAdd(&ps[e], ex[e] * inv);
    }
  }
  __syncthreads();
  if (tid < 8) { atomicAdd(&psum[tid], ps[tid]); atomicAdd(&fcnt[tid], fc[tid]); }
}

// ---------------- dispatch: stable rank within expert (token-major order), capacity drop ----------------
__global__ __launch_bounds__(256) void dispatch_kernel(
    const int2* __restrict__ e01, const float2* __restrict__ p01,
    int* __restrict__ tok_row, float* __restrict__ scale_row, int* __restrict__ counts) {
  __shared__ int lcnt[256][8];
  int tid = threadIdx.x;
  int my[8];
#pragma unroll
  for (int e = 0; e < 8; ++e) my[e] = 0;
  int base = tid * 64;  // 256 threads * 64 entries = 16384 = N*K, contiguous => stable
  for (int j = 0; j < 64; ++j) {
    int ent = base + j; int t = ent >> 1;
    int2 ee = e01[t];
    int ex = (ent & 1) ? ee.y : ee.x;
    my[ex]++;
  }
#pragma unroll
  for (int e = 0; e < 8; ++e) lcnt[tid][e] = my[e];
  __syncthreads();
  if (tid < 8) {
    int run = 0;
    for (int i = 0; i < 256; ++i) { int c = lcnt[i][tid]; lcnt[i][tid] = run; run += c; }
    counts[tid] = run < CAP ? run : CAP;
  }
  __syncthreads();
  int offs[8];
#pragma unroll
  for (int e = 0; e < 8; ++e) offs[e] = lcnt[tid][e];
  for (int j = 0; j < 64; ++j) {
    int ent = base + j; int t = ent >> 1; int k = ent & 1;
    int2 ee = e01[t];
    int ex = k ? ee.y : ee.x;
    float pr = k ? p01[t].y : p01[t].x;
    int pos = offs[ex]++;
    if (pos < CAP) {
      int row = NTOK + ex * CAP + pos;
      tok_row[row] = t;
      scale_row[row] = pr;
    }
  }
}

// ---------------- grouped GEMM, BMxBN tile, BK=64, 8 waves, 4-phase fine interleave ----------------
// 3 LDS buffers (one Sm array: A rows [0,BM), B rows [BM,BM+BN)). During step
// t: read buf t%3; issue 6 stage loads for K-tile t+2 into buf (t+2)%3 spread
// {2,2,1,1} over 4 phases. Phase = {ds_read this phase's frags, stage issue}
// -> barrier -> setprio(1) 8 MFMA setprio(0) -> barrier. End-of-step:
// vmcnt(6) (=> K-tile t+1 landed; FIFO retire) + barrier; tail vmcnt 6->0.
// WAR on buf(t+2)%3 is safe: its K-tile t-1 reads retired before step t-1's
// trailing barrier. Swizzle (R3-verified BK=64): stage row&7 = lane>>3,
// source chunk = (lane&7)^(lane>>3); read chunk = (kk*4 + lane>>4)^(row&7),
// kk=1 is byte-offset XOR 64. EPI==1: H = bf16(relu(acc)^2);
// EPI==2: atomicAdd(y[tok][col], acc*scale).
template <int BM, int BN, int KD, int NDT, int WNV, bool GATHER, int EPI>
__global__ __launch_bounds__(512, 2) void gemm_kernel(
    const __bf16* __restrict__ A, const __bf16* __restrict__ B,
    __bf16* __restrict__ Hout, float* __restrict__ Yout,
    const int* __restrict__ counts, const int* __restrict__ tok_row,
    const float* __restrict__ scale_row) {
  constexpr int NCT = NDT / BN;
  constexpr int T = KD / 64;          // K-tiles (16 or 22)
  constexpr int AI = BM / 8;          // A stage instrs per K-tile (1KB = 8 rows)
  constexpr int SH = NTOK / BM;
  constexpr int ET = CAP / BM;
  // XCD bijective remap + 4-rt chunks (nwg%8==0, nwg%(4*NCT)==0 hold)
  int nwg = gridDim.x;
  int lin = (blockIdx.x & 7) * (nwg >> 3) + (blockIdx.x >> 3);
  int rem = lin % (4 * NCT);
  int rt = (lin / (4 * NCT)) * 4 + (rem & 3);
  int ct = rem >> 2;

  int g, i0, rowbase;
  if (rt < SH) { g = 8; rowbase = 0; i0 = rt * BM; }
  else { int r = rt - SH; g = r / ET; i0 = (r % ET) * BM; rowbase = NTOK + g * CAP; }
  int cnt = (g == 8) ? NTOK : counts[g];
  if (i0 >= cnt) return;  // uniform early-exit

  __shared__ __align__(16) __bf16 Sm[3][(BM + BN) * 64];
  __shared__ int   toksL[BM];
  __shared__ float sclL[BM];

  int tid = threadIdx.x, lane = tid & 63, wid = tid >> 6;

  if (tid < BM) {
    int i = i0 + tid; if (i > cnt - 1) i = cnt - 1;  // pad rows duplicate last valid
    toksL[tid] = tok_row[rowbase + i];
    if (EPI == 2) sclL[tid] = scale_row[rowbase + i];
  }
  __syncthreads();

  // stage setup: instr j covers 8 rows x 128B; lane -> row j*8+(lane>>3),
  // chunk lane&7, source chunk XOR (lane>>3) [= row&7].
  const char* gsrc[6];
  int rsub = lane >> 3, csub = lane & 7;
  int csw = (csub ^ rsub) * 16;
  const char* Bg = (const char*)B + (size_t)g * NDT * KD * 2;
#pragma unroll
  for (int q = 0; q < 6; ++q) {
    int j = wid * 6 + q;
    if (j < AI) {
      int row = j * 8 + rsub;
      size_t arow = GATHER ? (size_t)toksL[row] : (size_t)(rowbase + i0 + row);
      gsrc[q] = (const char*)A + arow * (size_t)(KD * 2) + csw;
    } else {
      int rb = (j - AI) * 8 + rsub;
      gsrc[q] = Bg + (size_t)(ct * BN + rb) * (KD * 2) + csw;
    }
  }
  auto stageq = [&](int buf, int kt, int q) {
    load_lds16(gsrc[q] + (size_t)kt * 128,
               (char*)&Sm[buf][0] + (wid * 6 + q) * 1024);
  };

  f32x4 acc[4][4];
#pragma unroll
  for (int m2 = 0; m2 < 4; ++m2)
#pragma unroll
    for (int n2 = 0; n2 < 4; ++n2) acc[m2][n2] = f32x4{0.f, 0.f, 0.f, 0.f};

  int wr = wid / WNV, wc = wid % WNV;  // wave tile 64x64 at (wr*64, wc*64)
  int cs16 = ((lane >> 4) ^ (lane & 7)) * 16;   // kk=0 chunk; kk=1 = ^64
  int rdA[4], rdB[4];                            // byte offsets in Sm buffer
#pragma unroll
  for (int m2 = 0; m2 < 4; ++m2)
    rdA[m2] = (wr * 64 + m2 * 16 + (lane & 15)) * 128 + cs16;
#pragma unroll
  for (int n2 = 0; n2 < 4; ++n2)
    rdB[n2] = (BM + wc * 64 + n2 * 16 + (lane & 15)) * 128 + cs16;

  // prologue: K-tiles 0,1 staged into buf 0,1; wait kt0 (12 out -> <=6)
#pragma unroll
  for (int q = 0; q < 6; ++q) stageq(0, 0, q);
#pragma unroll
  for (int q = 0; q < 6; ++q) stageq(1, 1, q);
  asm volatile("s_waitcnt vmcnt(6)" ::: "memory");
  __builtin_amdgcn_s_barrier();
  __builtin_amdgcn_sched_barrier(0);

  int bufR = 0;
#pragma unroll 1
  for (int t = 0; t < T; ++t) {
    int bufW = bufR + 2; if (bufW >= 3) bufW -= 3;
    int kt2 = t + 2;
    bool st = kt2 < T;
    const char* Sb = (const char*)&Sm[bufR][0];
    bf16x8 a0, a1, b0, b1, b2, b3;
    // ---- phase 0: kk=0, m2 0-1 (6 ds_reads, 2 stage issues)
    a0 = *(const bf16x8*)(Sb + rdA[0]);
    a1 = *(const bf16x8*)(Sb + rdA[1]);
    b0 = *(const bf16x8*)(Sb + rdB[0]);
    b1 = *(const bf16x8*)(Sb + rdB[1]);
    b2 = *(const bf16x8*)(Sb + rdB[2]);
    b3 = *(const bf16x8*)(Sb + rdB[3]);
    if (st) { stageq(bufW, kt2, 0); stageq(bufW, kt2, 1); }
    BARS();
    MF8(0, 1);
    BARS();
    // ---- phase 1: kk=0, m2 2-3 (2 ds_reads, 2 stage issues)
    a0 = *(const bf16x8*)(Sb + rdA[2]);
    a1 = *(const bf16x8*)(Sb + rdA[3]);
    if (st) { stageq(bufW, kt2, 2); stageq(bufW, kt2, 3); }
    BARS();
    MF8(2, 3);
    BARS();
    // ---- phase 2: kk=1, m2 0-1 (6 ds_reads, 1 stage issue)
    a0 = *(const bf16x8*)(Sb + (rdA[0] ^ 64));
    a1 = *(const bf16x8*)(Sb + (rdA[1] ^ 64));
    b0 = *(const bf16x8*)(Sb + (rdB[0] ^ 64));
    b1 = *(const bf16x8*)(Sb + (rdB[1] ^ 64));
    b2 = *(const bf16x8*)(Sb + (rdB[2] ^ 64));
    b3 = *(const bf16x8*)(Sb + (rdB[3] ^ 64));
    if (st) stageq(bufW, kt2, 4);
    BARS();
    MF8(0, 1);
    BARS();
    // ---- phase 3: kk=1, m2 2-3 (2 ds_reads, 1 stage issue)
    a0 = *(const bf16x8*)(Sb + (rdA[2] ^ 64));
    a1 = *(const bf16x8*)(Sb + (rdA[3] ^ 64));
    if (st) stageq(bufW, kt2, 5);
    BARS();
    MF8(2, 3);
    // ---- end-of-step: ensure buf[(t+1)%3] landed before next step reads it
    if (t < T - 2)       { asm volatile("s_waitcnt vmcnt(6)" ::: "memory"); }
    else if (t == T - 2) { asm volatile("s_waitcnt vmcnt(0)" ::: "memory"); }
    if (t < T - 1) BARS();
    bufR = bufR + 1; if (bufR >= 3) bufR -= 3;
  }

  // epilogue; C/D frag: col = lane&15, row = (lane>>4)*4 + reg  [verified m89/m91]
#pragma unroll
  for (int m2 = 0; m2 < 4; ++m2) {
    int rb = wr * 64 + m2 * 16 + ((lane >> 4) << 2);
#pragma unroll
    for (int n2 = 0; n2 < 4; ++n2) {
      int col = ct * BN + wc * 64 + n2 * 16 + (lane & 15);
#pragma unroll
      for (int r = 0; r < 4; ++r) {
        int grow = i0 + rb + r;
        if (grow < cnt) {
          float v = acc[m2][n2][r];
          if constexpr (EPI == 1) {
            v = fmaxf(v, 0.f);
            Hout[(size_t)(rowbase + grow) * NDT + col] = (__bf16)(v * v);
          } else {
            atomicAdd(&Yout[(size_t)toksL[rb + r] * NDT + col], v * sclL[rb + r]);
          }
        }
      }
    }
  }
}

// ---------------- aux loss ----------------
__global__ void aux_kernel(const float* __restrict__ psum, const int* __restrict__ fcnt,
                           float* __restrict__ out) {
  float s = 0.f;
  for (int e = 0; e < 8; ++e) s += ((float)fcnt[e] / 8192.f) * (psum[e] / 8192.f);
  *out = 0.08f * s;  // AUX_COEF * E = 0.01 * 8
}

extern "C" void kernel_launch(void* const* d_in, const int* in_sizes, int n_in,
                              void* d_out, int out_size, void* d_ws, size_t ws_size,
                              hipStream_t stream) {
  const float* x      = (const float*)d_in[0];
  const float* rw     = (const float*)d_in[1];
  const float* wfc    = (const float*)d_in[2];
  const float* wproj  = (const float*)d_in[3];
  const float* wsfc   = (const float*)d_in[4];
  const float* wsproj = (const float*)d_in[5];
  float* y = (float*)d_out;

  char* ws = (char*)d_ws;
  size_t off = 0;
  auto alloc = [&](size_t bytes) {
    void* p = ws + off;
    off += (bytes + 1023) & ~(size_t)1023;
    return p;
  };
  __bf16* xbf      = (__bf16*)alloc((size_t)NTOK * DDIM * 2);          // 16 MB
  __bf16* B1       = (__bf16*)alloc((size_t)9 * HDIM * DDIM * 2);      // 26 MB [9][1408][1024]
  __bf16* B2       = (__bf16*)alloc((size_t)9 * DDIM * HDIM * 2);      // 26 MB [9][1024][1408]
  __bf16* H        = (__bf16*)alloc((size_t)NROWS * HDIM * 2);         // 81 MB
  int*    tok_row  = (int*)alloc((size_t)NROWS * 4);
  float*  scale_row= (float*)alloc((size_t)NROWS * 4);
  int2*   e01      = (int2*)alloc((size_t)NTOK * 8);
  float2* p01      = (float2*)alloc((size_t)NTOK * 8);
  int*    counts   = (int*)alloc(1024);
  float*  psum     = (float*)alloc(1024);
  int*    fcnt     = (int*)alloc(1024);
  (void)ws_size; (void)out_size; (void)in_sizes; (void)n_in;

  zero_kernel<<<2048, 256, 0, stream>>>(y, psum, fcnt);
  convx_kernel<<<4096, 256, 0, stream>>>(x, xbf);
  dim3 tb(32, 8);
  tconv_kernel<<<dim3(44, 32, 8), tb, 0, stream>>>(wfc, B1, 1024, 1408);
  tconv_kernel<<<dim3(44, 32, 1), tb, 0, stream>>>(wsfc, B1 + (size_t)8 * HDIM * DDIM, 1024, 1408);
  tconv_kernel<<<dim3(32, 44, 8), tb, 0, stream>>>(wproj, B2, 1408, 1024);
  tconv_kernel<<<dim3(32, 44, 1), tb, 0, stream>>>(wsproj, B2 + (size_t)8 * DDIM * HDIM, 1408, 1024);
  router_kernel<<<256, 256, 0, stream>>>(x, rw, e01, p01, tok_row, scale_row, psum, fcnt);
  dispatch_kernel<<<1, 256, 0, stream>>>(e01, p01, tok_row, scale_row, counts);
  // GEMM1: H = relu(gather(x) @ B1)^2 ; 256x128 tiles: (32 + 8*10) rt * 11 ct = 1232
  gemm_kernel<256, 128, 1024, 1408, 2, true, 1><<<1232, 512, 0, stream>>>(
      xbf, B1, H, nullptr, counts, tok_row, scale_row);
  // GEMM2: y[tok] += scale * (H @ B2) ; 128x256 tiles: (64 + 8*20) rt * 4 ct = 896
  gemm_kernel<128, 256, 1408, 1024, 4, false, 2><<<896, 512, 0, stream>>>(
      H, B2, nullptr, y, counts, tok_row, scale_row);
  aux_kernel<<<1, 1, 0, stream>>>(psum, fcnt, y + YN);
}

// Round 8
// 387.683 us; speedup vs baseline: 1.1483x; 1.1483x over previous
//
#include <hip/hip_runtime.h>

// MoE forward, MI355X. fp32 router/dispatch (exact top-k), bf16 MFMA grouped
// GEMMs (9 groups = 8 experts + shared), fp32-atomic scatter-combine.
// R7: staged-byte-model test. Both GEMMs 256x256 tiles (m248 config) to cut
// global->LDS staged bytes 31% (invariant ~5TB/s staging rate observed across
// R2-R6). Hidden dim padded 1408->1536 (B1 pad rows zeroed => H pad cols = 0
// => GEMM2 K-pad contributes exactly 0). Schedule frozen at R5's verified
// depth-3 counted-vmcnt pipeline (BK=32, 4 LDS bufs, vmcnt 8->4->0, LI=4).

#define NTOK 8192
#define DDIM 1024
#define HDIM 1408
#define HP   1536              // padded hidden (6*256)
#define CAP  2560
#define NROWS (NTOK + 8*CAP)   // 28672 GEMM rows: [0,8192) shared, then 8*2560 expert slots
#define YN   8388608           // NTOK*DDIM

typedef __bf16 bf16x8 __attribute__((ext_vector_type(8)));
typedef float  f32x4  __attribute__((ext_vector_type(4)));

typedef __attribute__((address_space(1))) void gvoid_t;
typedef __attribute__((address_space(3))) void svoid_t;

static __device__ __forceinline__ void load_lds16(const void* g, void* l) {
  // 16B per lane, LDS dest = wave-uniform base + lane*16 (linear)
  __builtin_amdgcn_global_load_lds((gvoid_t*)g, (svoid_t*)l, 16, 0, 0);
}

// ---------------- zero y + aux + accumulators ----------------
__global__ __launch_bounds__(256) void zero_kernel(float* __restrict__ y,
                                                   float* __restrict__ psum,
                                                   int* __restrict__ fcnt) {
  size_t idx = (size_t)blockIdx.x * 256 + threadIdx.x;
  float4 z = make_float4(0.f, 0.f, 0.f, 0.f);
  float4* p = (float4*)y;
#pragma unroll
  for (int j = 0; j < 4; ++j) p[idx + (size_t)j * 524288] = z;
  if (idx == 0) {
    y[YN] = 0.f;
    for (int e = 0; e < 8; ++e) { psum[e] = 0.f; fcnt[e] = 0; }
  }
}

// ---------------- zero B1 pad rows [1408,1536) x 1024 per expert ----------------
__global__ __launch_bounds__(256) void zpad_kernel(__bf16* __restrict__ B1) {
  int idx = blockIdx.x * 256 + threadIdx.x;     // 576 blocks -> 147456 thr x 8 elems
  int e = idx >> 14;                            // 16384 chunks of 8 per expert
  int w = idx & 16383;
  size_t off = (size_t)e * HP * 1024 + (size_t)(HDIM + (w >> 7)) * 1024 + (w & 127) * 8;
  *(float4*)(B1 + off) = make_float4(0.f, 0.f, 0.f, 0.f);
}

// ---------------- fp32 -> bf16 (x) ----------------
__global__ __launch_bounds__(256) void convx_kernel(const float* __restrict__ in,
                                                    __bf16* __restrict__ out) {
  size_t i = ((size_t)blockIdx.x * 256 + threadIdx.x) * 8;
  float4 a = *(const float4*)(in + i);
  float4 b = *(const float4*)(in + i + 4);
  bf16x8 o;
  o[0] = (__bf16)a.x; o[1] = (__bf16)a.y; o[2] = (__bf16)a.z; o[3] = (__bf16)a.w;
  o[4] = (__bf16)b.x; o[5] = (__bf16)b.y; o[6] = (__bf16)b.z; o[7] = (__bf16)b.w;
  *(bf16x8*)(out + i) = o;
}

// ---- transpose + convert: in[R][C] f32 -> out[C][R(stride OS)] bf16, expert z-stride zs ----
__global__ __launch_bounds__(256) void tconv_kernel(const float* __restrict__ in,
                                                    __bf16* __restrict__ out,
                                                    int R, int C, int OS, size_t zs) {
  __shared__ float t[32][33];
  const float* ip = in + (size_t)blockIdx.z * R * C;
  __bf16* op = out + (size_t)blockIdx.z * zs;
  int c0 = blockIdx.x * 32, r0 = blockIdx.y * 32;
  int tx = threadIdx.x, ty = threadIdx.y;  // block (32,8)
#pragma unroll
  for (int k2 = 0; k2 < 4; ++k2)
    t[ty + k2 * 8][tx] = ip[(size_t)(r0 + ty + k2 * 8) * C + c0 + tx];
  __syncthreads();
#pragma unroll
  for (int k2 = 0; k2 < 4; ++k2)
    op[(size_t)(c0 + ty + k2 * 8) * OS + r0 + tx] = (__bf16)t[tx][ty + k2 * 8];
}

// ---------------- router: fp32 logits, softmax, top-2, renorm, aux stats ----------------
__global__ __launch_bounds__(256) void router_kernel(
    const float* __restrict__ x, const float* __restrict__ rw,
    int2* __restrict__ e01, float2* __restrict__ p01,
    int* __restrict__ tok_row, float* __restrict__ scale_row,
    float* __restrict__ psum, int* __restrict__ fcnt) {
  __shared__ float rwl[8 * 1024];
  __shared__ float ps[8];
  __shared__ int fc[8];
  int tid = threadIdx.x;
  if (tid < 8) { ps[tid] = 0.f; fc[tid] = 0; }
  float4* rl4 = (float4*)rwl;
  const float4* rg4 = (const float4*)rw;
#pragma unroll
  for (int j = 0; j < 8; ++j) rl4[tid + 256 * j] = rg4[tid + 256 * j];
  __syncthreads();
  int lane = tid & 63, wid = tid >> 6;
  for (int it = 0; it < 8; ++it) {
    int t = blockIdx.x * 32 + wid * 8 + it;
    const float4* xt = (const float4*)(x + (size_t)t * DDIM);
    float a[8];
#pragma unroll
    for (int e = 0; e < 8; ++e) a[e] = 0.f;
#pragma unroll
    for (int jj = 0; jj < 4; ++jj) {
      float4 v = xt[lane * 4 + jj];
#pragma unroll
      for (int e = 0; e < 8; ++e) {
        float4 w = rl4[e * 256 + lane * 4 + jj];
        a[e] += v.x * w.x + v.y * w.y + v.z * w.z + v.w * w.w;
      }
    }
#pragma unroll
    for (int off = 32; off >= 1; off >>= 1)
#pragma unroll
      for (int e = 0; e < 8; ++e) a[e] += __shfl_xor(a[e], off);
    if (lane == 0) {
      int am = 0; float m = a[0];
      for (int e = 1; e < 8; ++e) if (a[e] > m) { m = a[e]; am = e; }
      float s = 0.f, ex[8];
      for (int e = 0; e < 8; ++e) { ex[e] = expf(a[e] - m); s += ex[e]; }
      float inv = 1.f / s;
      int am2 = -1; float m2 = -3.4e38f;
      for (int e = 0; e < 8; ++e) if (e != am && a[e] > m2) { m2 = a[e]; am2 = e; }
      float p0 = ex[am] * inv, p1 = ex[am2] * inv;
      float rn = 1.f / (p0 + p1 + 1e-9f);
      e01[t] = make_int2(am, am2);
      p01[t] = make_float2(p0 * rn, p1 * rn);
      tok_row[t] = t;            // shared-group rows: identity gather, weight 1
      scale_row[t] = 1.f;
      atomicAdd(&fc[am], 1);
      for (int e = 0; e < 8; ++e) atomicAdd(&ps[e], ex[e] * inv);
    }
  }
  __syncthreads();
  if (tid < 8) { atomicAdd(&psum[tid], ps[tid]); atomicAdd(&fcnt[tid], fc[tid]); }
}

// ---------------- dispatch: stable rank within expert (token-major order), capacity drop ----------------
__global__ __launch_bounds__(256) void dispatch_kernel(
    const int2* __restrict__ e01, const float2* __restrict__ p01,
    int* __restrict__ tok_row, float* __restrict__ scale_row, int* __restrict__ counts) {
  __shared__ int lcnt[256][8];
  int tid = threadIdx.x;
  int my[8];
#pragma unroll
  for (int e = 0; e < 8; ++e) my[e] = 0;
  int base = tid * 64;  // 256 threads * 64 entries = 16384 = N*K, contiguous => stable
  for (int j = 0; j < 64; ++j) {
    int ent = base + j; int t = ent >> 1;
    int2 ee = e01[t];
    int ex = (ent & 1) ? ee.y : ee.x;
    my[ex]++;
  }
#pragma unroll
  for (int e = 0; e < 8; ++e) lcnt[tid][e] = my[e];
  __syncthreads();
  if (tid < 8) {
    int run = 0;
    for (int i = 0; i < 256; ++i) { int c = lcnt[i][tid]; lcnt[i][tid] = run; run += c; }
    counts[tid] = run < CAP ? run : CAP;
  }
  __syncthreads();
  int offs[8];
#pragma unroll
  for (int e = 0; e < 8; ++e) offs[e] = lcnt[tid][e];
  for (int j = 0; j < 64; ++j) {
    int ent = base + j; int t = ent >> 1; int k = ent & 1;
    int2 ee = e01[t];
    int ex = k ? ee.y : ee.x;
    float pr = k ? p01[t].y : p01[t].x;
    int pos = offs[ex]++;
    if (pos < CAP) {
      int row = NTOK + ex * CAP + pos;
      tok_row[row] = t;
      scale_row[row] = pr;
    }
  }
}

// ---------------- grouped GEMM, 256x256 tile, BK=32, 8 waves, depth-3 pipeline ----------------
// R5-verified schedule, widened: 4 LDS buffers; stage(t+3) at step t; one raw
// s_barrier per step. LI=4 loads/wave/stage: steady vmcnt(8) => stage t+1
// complete; drain tail 8 -> 4 -> 0. Wave tile 64x128 (4 M-frags x 8 N-frags).
// XOR swizzle (BK=32): LDS[row][c'] holds global chunk c'^((row>>1)&3).
// EPI==1: H = bf16(relu(acc)^2)   EPI==2: atomicAdd(y[tok][col], acc*scale)
template <int KD, int NDT, bool GATHER, int EPI>
__global__ __launch_bounds__(512, 2) void gemm_kernel(
    const __bf16* __restrict__ A, const __bf16* __restrict__ B,
    __bf16* __restrict__ Hout, float* __restrict__ Yout,
    const int* __restrict__ counts, const int* __restrict__ tok_row,
    const float* __restrict__ scale_row) {
  constexpr int BM = 256, BN = 256;
  constexpr int NCT = NDT / BN;       // 6 (GEMM1) or 4 (GEMM2)
  constexpr int T = KD / 32;          // 32 or 48 K-steps
  constexpr int AI = BM / 16;         // 16 A stage instrs per step
  constexpr int LI = 4;               // per-wave stage instrs
  constexpr int SH = NTOK / BM;       // 32 shared row-tiles
  constexpr int ET = CAP / BM;        // 10 expert row-tiles (worst case)
  // XCD bijective remap + 4-rt chunks (nwg%8==0)
  int nwg = gridDim.x;
  int lin = (blockIdx.x & 7) * (nwg >> 3) + (blockIdx.x >> 3);
  int rem = lin % (4 * NCT);
  int rt = (lin / (4 * NCT)) * 4 + (rem & 3);
  int ct = rem >> 2;

  int g, i0, rowbase;
  if (rt < SH) { g = 8; rowbase = 0; i0 = rt * BM; }
  else { int r = rt - SH; g = r / ET; i0 = (r % ET) * BM; rowbase = NTOK + g * CAP; }
  int cnt = (g == 8) ? NTOK : counts[g];
  if (i0 >= cnt) return;  // uniform early-exit

  __shared__ __align__(16) __bf16 As[4][BM * 32];   // 64 KB
  __shared__ __align__(16) __bf16 Bs[4][BN * 32];   // 64 KB
  __shared__ int   toksL[BM];
  __shared__ float sclL[BM];

  int tid = threadIdx.x, lane = tid & 63, wid = tid >> 6;

  if (tid < BM) {
    int i = i0 + tid; if (i > cnt - 1) i = cnt - 1;  // pad rows duplicate last valid
    toksL[tid] = tok_row[rowbase + i];
    if (EPI == 2) sclL[tid] = scale_row[rowbase + i];
  }
  __syncthreads();

  // per-lane stage setup: instr j covers 16 rows x 64B; lane -> row j*16+(lane>>2),
  // chunk (lane&3), source chunk XOR-swizzled by (row>>1)&3.
  const char* gsrc[LI];
  int ldsoff[LI];
  bool isA[LI];
  const char* Bg = (const char*)B + (size_t)g * NDT * KD * 2;
#pragma unroll
  for (int q = 0; q < LI; ++q) {
    int j = wid * LI + q;
    int rsub = lane >> 2;
    int chunk = lane & 3;
    if (j < AI) {
      int row = j * 16 + rsub;
      size_t arow = GATHER ? (size_t)toksL[row] : (size_t)(rowbase + i0 + row);
      int csw = chunk ^ ((row >> 1) & 3);
      gsrc[q] = (const char*)A + arow * (size_t)(KD * 2) + csw * 16;
      ldsoff[q] = j * 1024;
      isA[q] = true;
    } else {
      int jb = j - AI;
      int row = jb * 16 + rsub;
      int ib = ct * BN + row;
      int csw = chunk ^ ((row >> 1) & 3);
      gsrc[q] = Bg + (size_t)ib * (KD * 2) + csw * 16;
      ldsoff[q] = jb * 1024;
      isA[q] = false;
    }
  }

  f32x4 acc[4][8];
#pragma unroll
  for (int m2 = 0; m2 < 4; ++m2)
#pragma unroll
    for (int n2 = 0; n2 < 8; ++n2) acc[m2][n2] = f32x4{0.f, 0.f, 0.f, 0.f};

  int wr = wid >> 1, wc = wid & 1;  // wave tile 64x128 at (wr*64, wc*128)
  // hoisted LDS read byte-offsets within a buffer
  int rdA[4], rdB[8];
#pragma unroll
  for (int m2 = 0; m2 < 4; ++m2) {
    int row = wr * 64 + m2 * 16 + (lane & 15);
    int cs = (lane >> 4) ^ ((row >> 1) & 3);
    rdA[m2] = row * 64 + cs * 16;
  }
#pragma unroll
  for (int n2 = 0; n2 < 8; ++n2) {
    int row = wc * 128 + n2 * 16 + (lane & 15);
    int cs = (lane >> 4) ^ ((row >> 1) & 3);
    rdB[n2] = row * 64 + cs * 16;
  }

  auto stage = [&](int buf, int t) {
#pragma unroll
    for (int q = 0; q < LI; ++q) {
      char* l = (char*)(isA[q] ? &As[buf][0] : &Bs[buf][0]) + ldsoff[q];
      load_lds16(gsrc[q] + (size_t)t * 64, l);
    }
  };
  auto compute = [&](int buf) {
    bf16x8 af[4], bfr[8];
#pragma unroll
    for (int m2 = 0; m2 < 4; ++m2)
      af[m2] = *(const bf16x8*)((const char*)&As[buf][0] + rdA[m2]);
#pragma unroll
    for (int n2 = 0; n2 < 8; ++n2)
      bfr[n2] = *(const bf16x8*)((const char*)&Bs[buf][0] + rdB[n2]);
    __builtin_amdgcn_s_setprio(1);
#pragma unroll
    for (int m2 = 0; m2 < 4; ++m2)
#pragma unroll
      for (int n2 = 0; n2 < 8; ++n2)
        acc[m2][n2] = __builtin_amdgcn_mfma_f32_16x16x32_bf16(af[m2], bfr[n2], acc[m2][n2], 0, 0, 0);
    __builtin_amdgcn_s_setprio(0);
  };
  auto syncstep = [&](int n) {   // wait own loads (all but newest n), then collective barrier
    if (n == 0)      asm volatile("s_waitcnt vmcnt(0)" ::: "memory");
    else if (n == 4) asm volatile("s_waitcnt vmcnt(4)" ::: "memory");
    else             asm volatile("s_waitcnt vmcnt(8)" ::: "memory");
    __builtin_amdgcn_s_barrier();
    __builtin_amdgcn_sched_barrier(0);  // raw s_barrier is not an LLVM fence: pin reads below
  };

  // prologue: fill pipeline 3 deep; vmcnt(8) => buf0's own loads complete
  stage(0, 0);
  stage(1, 1);
  stage(2, 2);
  syncstep(8);
  // steady state: stage(t+3) in flight; vmcnt(8) => stage(t+1) complete
#pragma unroll 4
  for (int t = 0; t < T - 3; ++t) {
    stage((t + 3) & 3, t + 3);
    compute(t & 3);
    syncstep(8);
  }
  // drain tail: no new stages; 8 -> 4 -> 0 outstanding
  compute((T - 3) & 3);
  syncstep(4);                 // stage(T-2) complete
  compute((T - 2) & 3);
  syncstep(0);                 // stage(T-1) complete
  compute((T - 1) & 3);

  // epilogue; C/D frag: col = lane&15, row = (lane>>4)*4 + reg  [verified m89/m91]
#pragma unroll
  for (int m2 = 0; m2 < 4; ++m2) {
    int rb = wr * 64 + m2 * 16 + ((lane >> 4) << 2);
#pragma unroll
    for (int n2 = 0; n2 < 8; ++n2) {
      int col = ct * BN + wc * 128 + n2 * 16 + (lane & 15);
#pragma unroll
      for (int r = 0; r < 4; ++r) {
        int grow = i0 + rb + r;
        if (grow < cnt) {
          float v = acc[m2][n2][r];
          if constexpr (EPI == 1) {
            v = fmaxf(v, 0.f);
            Hout[(size_t)(rowbase + grow) * NDT + col] = (__bf16)(v * v);
          } else {
            atomicAdd(&Yout[(size_t)toksL[rb + r] * NDT + col], v * sclL[rb + r]);
          }
        }
      }
    }
  }
}

// ---------------- aux loss ----------------
__global__ void aux_kernel(const float* __restrict__ psum, const int* __restrict__ fcnt,
                           float* __restrict__ out) {
  float s = 0.f;
  for (int e = 0; e < 8; ++e) s += ((float)fcnt[e] / 8192.f) * (psum[e] / 8192.f);
  *out = 0.08f * s;  // AUX_COEF * E = 0.01 * 8
}

extern "C" void kernel_launch(void* const* d_in, const int* in_sizes, int n_in,
                              void* d_out, int out_size, void* d_ws, size_t ws_size,
                              hipStream_t stream) {
  const float* x      = (const float*)d_in[0];
  const float* rw     = (const float*)d_in[1];
  const float* wfc    = (const float*)d_in[2];
  const float* wproj  = (const float*)d_in[3];
  const float* wsfc   = (const float*)d_in[4];
  const float* wsproj = (const float*)d_in[5];
  float* y = (float*)d_out;

  char* ws = (char*)d_ws;
  size_t off = 0;
  auto alloc = [&](size_t bytes) {
    void* p = ws + off;
    off += (bytes + 1023) & ~(size_t)1023;
    return p;
  };
  __bf16* xbf      = (__bf16*)alloc((size_t)NTOK * DDIM * 2);          // 16 MB
  __bf16* B1       = (__bf16*)alloc((size_t)9 * HP * DDIM * 2);        // 28 MB [9][1536][1024]
  __bf16* B2       = (__bf16*)alloc((size_t)9 * DDIM * HP * 2);        // 28 MB [9][1024][1536]
  __bf16* H        = (__bf16*)alloc((size_t)NROWS * HP * 2);           // 88 MB [rows][1536]
  int*    tok_row  = (int*)alloc((size_t)NROWS * 4);
  float*  scale_row= (float*)alloc((size_t)NROWS * 4);
  int2*   e01      = (int2*)alloc((size_t)NTOK * 8);
  float2* p01      = (float2*)alloc((size_t)NTOK * 8);
  int*    counts   = (int*)alloc(1024);
  float*  psum     = (float*)alloc(1024);
  int*    fcnt     = (int*)alloc(1024);
  (void)ws_size; (void)out_size; (void)in_sizes; (void)n_in;

  zero_kernel<<<2048, 256, 0, stream>>>(y, psum, fcnt);
  zpad_kernel<<<576, 256, 0, stream>>>(B1);
  convx_kernel<<<4096, 256, 0, stream>>>(x, xbf);
  dim3 tb(32, 8);
  // B1: wfc [e][1024][1408] -> [e][1536(row=h)][1024(k=d)], pad rows zeroed above
  tconv_kernel<<<dim3(44, 32, 8), tb, 0, stream>>>(wfc, B1, 1024, 1408, 1024, (size_t)HP * 1024);
  tconv_kernel<<<dim3(44, 32, 1), tb, 0, stream>>>(wsfc, B1 + (size_t)8 * HP * 1024, 1024, 1408, 1024, (size_t)HP * 1024);
  // B2: wproj [e][1408][1024] -> [e][1024(row=d)][1536(k=h)], pad cols harmless (x0 in MFMA)
  tconv_kernel<<<dim3(32, 44, 8), tb, 0, stream>>>(wproj, B2, 1408, 1024, HP, (size_t)1024 * HP);
  tconv_kernel<<<dim3(32, 44, 1), tb, 0, stream>>>(wsproj, B2 + (size_t)8 * 1024 * HP, 1408, 1024, HP, (size_t)1024 * HP);
  router_kernel<<<256, 256, 0, stream>>>(x, rw, e01, p01, tok_row, scale_row, psum, fcnt);
  dispatch_kernel<<<1, 256, 0, stream>>>(e01, p01, tok_row, scale_row, counts);
  // GEMM1: H = relu(gather(x) @ B1)^2 ; 256x256 tiles: (32 + 8*10) rt * 6 ct = 672
  gemm_kernel<1024, HP, true, 1><<<672, 512, 0, stream>>>(
      xbf, B1, H, nullptr, counts, tok_row, scale_row);
  // GEMM2: y[tok] += scale * (H @ B2) ; 256x256 tiles: 112 rt * 4 ct = 448
  gemm_kernel<HP, 1024, false, 2><<<448, 512, 0, stream>>>(
      H, B2, nullptr, y, counts, tok_row, scale_row);
  aux_kernel<<<1, 1, 0, stream>>>(psum, fcnt, y + YN);
}

// Round 9
// 324.345 us; speedup vs baseline: 1.3725x; 1.1953x over previous
//
#include <hip/hip_runtime.h>

// MoE forward, MI355X. fp32 router/dispatch (exact top-k), bf16 MFMA grouped
// GEMMs (9 groups = 8 experts + shared), fp32-atomic scatter-combine.
// R8: residency theory. m97-replica GEMM: 128x128 tile, BK=64, 4 waves,
// SINGLE-buffered 33KB LDS, plain stage->sync->compute->sync (compiler emits
// waitcnts), __launch_bounds__(256,4) => 4 blocks/CU (16 waves/CU). Cross-
// block overlap hides DMA latency (m97/m114: 3-4 resident blocks = 22 B/cyc/CU
// staging vs our 5-9 at 1-2 blocks). Swizzle + XCD remap kept (verified).

#define NTOK 8192
#define DDIM 1024
#define HDIM 1408
#define CAP  2560
#define NROWS (NTOK + 8*CAP)   // 28672 GEMM rows: [0,8192) shared, then 8*2560 expert slots
#define YN   8388608           // NTOK*DDIM

typedef __bf16 bf16x8 __attribute__((ext_vector_type(8)));
typedef float  f32x4  __attribute__((ext_vector_type(4)));

typedef __attribute__((address_space(1))) void gvoid_t;
typedef __attribute__((address_space(3))) void svoid_t;

static __device__ __forceinline__ void load_lds16(const void* g, void* l) {
  // 16B per lane, LDS dest = wave-uniform base + lane*16 (linear)
  __builtin_amdgcn_global_load_lds((gvoid_t*)g, (svoid_t*)l, 16, 0, 0);
}

// ---------------- zero y + aux + accumulators ----------------
__global__ __launch_bounds__(256) void zero_kernel(float* __restrict__ y,
                                                   float* __restrict__ psum,
                                                   int* __restrict__ fcnt) {
  size_t idx = (size_t)blockIdx.x * 256 + threadIdx.x;
  float4 z = make_float4(0.f, 0.f, 0.f, 0.f);
  float4* p = (float4*)y;
#pragma unroll
  for (int j = 0; j < 4; ++j) p[idx + (size_t)j * 524288] = z;
  if (idx == 0) {
    y[YN] = 0.f;
    for (int e = 0; e < 8; ++e) { psum[e] = 0.f; fcnt[e] = 0; }
  }
}

// ---------------- fp32 -> bf16 (x) ----------------
__global__ __launch_bounds__(256) void convx_kernel(const float* __restrict__ in,
                                                    __bf16* __restrict__ out) {
  size_t i = ((size_t)blockIdx.x * 256 + threadIdx.x) * 8;
  float4 a = *(const float4*)(in + i);
  float4 b = *(const float4*)(in + i + 4);
  bf16x8 o;
  o[0] = (__bf16)a.x; o[1] = (__bf16)a.y; o[2] = (__bf16)a.z; o[3] = (__bf16)a.w;
  o[4] = (__bf16)b.x; o[5] = (__bf16)b.y; o[6] = (__bf16)b.z; o[7] = (__bf16)b.w;
  *(bf16x8*)(out + i) = o;
}

// ---------------- transpose + convert weights: in[R][C] f32 -> out[C][R] bf16 ----------------
__global__ __launch_bounds__(256) void tconv_kernel(const float* __restrict__ in,
                                                    __bf16* __restrict__ out, int R, int C) {
  __shared__ float t[32][33];
  size_t mo = (size_t)blockIdx.z * R * C;
  const float* ip = in + mo;
  __bf16* op = out + mo;
  int c0 = blockIdx.x * 32, r0 = blockIdx.y * 32;
  int tx = threadIdx.x, ty = threadIdx.y;  // block (32,8)
#pragma unroll
  for (int k2 = 0; k2 < 4; ++k2)
    t[ty + k2 * 8][tx] = ip[(size_t)(r0 + ty + k2 * 8) * C + c0 + tx];
  __syncthreads();
#pragma unroll
  for (int k2 = 0; k2 < 4; ++k2)
    op[(size_t)(c0 + ty + k2 * 8) * R + r0 + tx] = (__bf16)t[tx][ty + k2 * 8];
}

// ---------------- router: fp32 logits, softmax, top-2, renorm, aux stats ----------------
__global__ __launch_bounds__(256) void router_kernel(
    const float* __restrict__ x, const float* __restrict__ rw,
    int2* __restrict__ e01, float2* __restrict__ p01,
    int* __restrict__ tok_row, float* __restrict__ scale_row,
    float* __restrict__ psum, int* __restrict__ fcnt) {
  __shared__ float rwl[8 * 1024];
  __shared__ float ps[8];
  __shared__ int fc[8];
  int tid = threadIdx.x;
  if (tid < 8) { ps[tid] = 0.f; fc[tid] = 0; }
  float4* rl4 = (float4*)rwl;
  const float4* rg4 = (const float4*)rw;
#pragma unroll
  for (int j = 0; j < 8; ++j) rl4[tid + 256 * j] = rg4[tid + 256 * j];
  __syncthreads();
  int lane = tid & 63, wid = tid >> 6;
  for (int it = 0; it < 8; ++it) {
    int t = blockIdx.x * 32 + wid * 8 + it;
    const float4* xt = (const float4*)(x + (size_t)t * DDIM);
    float a[8];
#pragma unroll
    for (int e = 0; e < 8; ++e) a[e] = 0.f;
#pragma unroll
    for (int jj = 0; jj < 4; ++jj) {
      float4 v = xt[lane * 4 + jj];
#pragma unroll
      for (int e = 0; e < 8; ++e) {
        float4 w = rl4[e * 256 + lane * 4 + jj];
        a[e] += v.x * w.x + v.y * w.y + v.z * w.z + v.w * w.w;
      }
    }
#pragma unroll
    for (int off = 32; off >= 1; off >>= 1)
#pragma unroll
      for (int e = 0; e < 8; ++e) a[e] += __shfl_xor(a[e], off);
    if (lane == 0) {
      int am = 0; float m = a[0];
      for (int e = 1; e < 8; ++e) if (a[e] > m) { m = a[e]; am = e; }
      float s = 0.f, ex[8];
      for (int e = 0; e < 8; ++e) { ex[e] = expf(a[e] - m); s += ex[e]; }
      float inv = 1.f / s;
      int am2 = -1; float m2 = -3.4e38f;
      for (int e = 0; e < 8; ++e) if (e != am && a[e] > m2) { m2 = a[e]; am2 = e; }
      float p0 = ex[am] * inv, p1 = ex[am2] * inv;
      float rn = 1.f / (p0 + p1 + 1e-9f);
      e01[t] = make_int2(am, am2);
      p01[t] = make_float2(p0 * rn, p1 * rn);
      tok_row[t] = t;            // shared-group rows: identity gather, weight 1
      scale_row[t] = 1.f;
      atomicAdd(&fc[am], 1);
      for (int e = 0; e < 8; ++e) atomicAdd(&ps[e], ex[e] * inv);
    }
  }
  __syncthreads();
  if (tid < 8) { atomicAdd(&psum[tid], ps[tid]); atomicAdd(&fcnt[tid], fc[tid]); }
}

// ---------------- dispatch: stable rank within expert (token-major order), capacity drop ----------------
__global__ __launch_bounds__(256) void dispatch_kernel(
    const int2* __restrict__ e01, const float2* __restrict__ p01,
    int* __restrict__ tok_row, float* __restrict__ scale_row, int* __restrict__ counts) {
  __shared__ int lcnt[256][8];
  int tid = threadIdx.x;
  int my[8];
#pragma unroll
  for (int e = 0; e < 8; ++e) my[e] = 0;
  int base = tid * 64;  // 256 threads * 64 entries = 16384 = N*K, contiguous => stable
  for (int j = 0; j < 64; ++j) {
    int ent = base + j; int t = ent >> 1;
    int2 ee = e01[t];
    int ex = (ent & 1) ? ee.y : ee.x;
    my[ex]++;
  }
#pragma unroll
  for (int e = 0; e < 8; ++e) lcnt[tid][e] = my[e];
  __syncthreads();
  if (tid < 8) {
    int run = 0;
    for (int i = 0; i < 256; ++i) { int c = lcnt[i][tid]; lcnt[i][tid] = run; run += c; }
    counts[tid] = run < CAP ? run : CAP;
  }
  __syncthreads();
  int offs[8];
#pragma unroll
  for (int e = 0; e < 8; ++e) offs[e] = lcnt[tid][e];
  for (int j = 0; j < 64; ++j) {
    int ent = base + j; int t = ent >> 1; int k = ent & 1;
    int2 ee = e01[t];
    int ex = k ? ee.y : ee.x;
    float pr = k ? p01[t].y : p01[t].x;
    int pos = offs[ex]++;
    if (pos < CAP) {
      int row = NTOK + ex * CAP + pos;
      tok_row[row] = t;
      scale_row[row] = pr;
    }
  }
}

// ---------------- grouped GEMM, 128x128 tile, BK=64, 4 waves, single-buffer (m97 structure) ----------------
// Per K-step: 8 global_load_lds/wave -> __syncthreads (compiler emits
// vmcnt(0)) -> 16 ds_read_b128 + 32 MFMA -> __syncthreads. Latency hiding
// comes from 4 resident blocks/CU (33KB LDS, <=128 VGPR), not from intra-
// block pipelining. XOR chunk-swizzle: LDS[row][c] = global[row][c^(row&7)]
// (16B chunks), staged via swizzled per-lane SOURCE, read with matching XOR.
// EPI==1: H = bf16(relu(acc)^2)   EPI==2: atomicAdd(y[tok][col], acc*scale)
template <int KD, int NDT, bool GATHER, int EPI>
__global__ __launch_bounds__(256, 4) void gemm_kernel(
    const __bf16* __restrict__ A, const __bf16* __restrict__ B,
    __bf16* __restrict__ Hout, float* __restrict__ Yout,
    const int* __restrict__ counts, const int* __restrict__ tok_row,
    const float* __restrict__ scale_row) {
  constexpr int NCT = NDT / 128;
  constexpr int SH = NTOK / 128;   // 64 shared row-tiles
  constexpr int ET = CAP / 128;    // 20 expert row-tiles (worst case)
  // XCD bijective remap + 4-rt chunks (nwg%8==0, nwg%(4*NCT)==0 hold)
  int nwg = gridDim.x;
  int lin = (blockIdx.x & 7) * (nwg >> 3) + (blockIdx.x >> 3);
  int rem = lin % (4 * NCT);
  int rt = (lin / (4 * NCT)) * 4 + (rem & 3);
  int ct = rem >> 2;

  int g, i0, rowbase;
  if (rt < SH) { g = 8; rowbase = 0; i0 = rt << 7; }
  else { int r = rt - SH; g = r / ET; i0 = (r % ET) << 7; rowbase = NTOK + g * CAP; }
  int cnt = (g == 8) ? NTOK : counts[g];
  if (i0 >= cnt) return;  // uniform early-exit

  __shared__ __align__(16) __bf16 As[128 * 64];   // 16 KB
  __shared__ __align__(16) __bf16 Bs[128 * 64];   // 16 KB
  __shared__ int   toksL[128];
  __shared__ float sclL[128];

  int tid = threadIdx.x, lane = tid & 63, wid = tid >> 6;

  if (tid < 128) {
    int i = i0 + tid; if (i > cnt - 1) i = cnt - 1;  // pad rows duplicate last valid
    toksL[tid] = tok_row[rowbase + i];
    if (EPI == 2) sclL[tid] = scale_row[rowbase + i];
  }
  __syncthreads();

  // staging pointers: 8 lanes cover one 128B k-row; 16B chunk swizzled by row&7
  int rsub = lane >> 3, csub = lane & 7;
  int csw = (csub ^ rsub) * 16;
  const char* aP[4];
  const char* bP[4];
  const char* Bg = (const char*)B + (size_t)g * NDT * KD * 2;
#pragma unroll
  for (int t = 0; t < 4; ++t) {
    int ia = wid * 32 + t * 8 + rsub;
    size_t arow = GATHER ? (size_t)toksL[ia] : (size_t)(rowbase + i0 + ia);
    aP[t] = (const char*)A + arow * (size_t)(KD * 2) + csw;
    int ib = ct * 128 + wid * 32 + t * 8 + rsub;
    bP[t] = Bg + (size_t)ib * (KD * 2) + csw;
  }

  f32x4 acc[4][4];
#pragma unroll
  for (int m2 = 0; m2 < 4; ++m2)
#pragma unroll
    for (int n2 = 0; n2 < 4; ++n2) acc[m2][n2] = f32x4{0.f, 0.f, 0.f, 0.f};

  int wr = wid >> 1, wc = wid & 1;   // wave tile 64x64 at (wr*64, wc*64)
  // hoisted LDS read offsets (element units); chunk' = chunk ^ (row&7), row&7 == lane&7
  int rA[4], rB[4], cS[2];
#pragma unroll
  for (int m2 = 0; m2 < 4; ++m2) rA[m2] = (wr * 64 + m2 * 16 + (lane & 15)) * 64;
#pragma unroll
  for (int n2 = 0; n2 < 4; ++n2) rB[n2] = (wc * 64 + n2 * 16 + (lane & 15)) * 64;
#pragma unroll
  for (int kk = 0; kk < 2; ++kk) cS[kk] = ((kk * 4 + (lane >> 4)) ^ (lane & 7)) * 8;

  // m97 structure: stage -> sync -> compute -> sync, single buffer.
  for (int k0 = 0; k0 < KD; k0 += 64) {
    size_t kb = (size_t)k0 * 2;
#pragma unroll
    for (int t = 0; t < 4; ++t) {
      load_lds16(aP[t] + kb, &As[(wid * 32 + t * 8) * 64]);
      load_lds16(bP[t] + kb, &Bs[(wid * 32 + t * 8) * 64]);
    }
    __syncthreads();   // compiler inserts s_waitcnt vmcnt(0) before barrier
#pragma unroll
    for (int kk = 0; kk < 2; ++kk) {
      bf16x8 af[4], bfr[4];
#pragma unroll
      for (int m2 = 0; m2 < 4; ++m2) af[m2] = *(const bf16x8*)&As[rA[m2] + cS[kk]];
#pragma unroll
      for (int n2 = 0; n2 < 4; ++n2) bfr[n2] = *(const bf16x8*)&Bs[rB[n2] + cS[kk]];
#pragma unroll
      for (int m2 = 0; m2 < 4; ++m2)
#pragma unroll
        for (int n2 = 0; n2 < 4; ++n2)
          acc[m2][n2] = __builtin_amdgcn_mfma_f32_16x16x32_bf16(af[m2], bfr[n2], acc[m2][n2], 0, 0, 0);
    }
    __syncthreads();   // protect LDS reuse next iteration
  }

  // epilogue; C/D frag: col = lane&15, row = (lane>>4)*4 + reg  [verified m89/m91]
#pragma unroll
  for (int m2 = 0; m2 < 4; ++m2) {
    int rb = wr * 64 + m2 * 16 + ((lane >> 4) << 2);
#pragma unroll
    for (int n2 = 0; n2 < 4; ++n2) {
      int col = ct * 128 + wc * 64 + n2 * 16 + (lane & 15);
#pragma unroll
      for (int r = 0; r < 4; ++r) {
        int grow = i0 + rb + r;
        if (grow < cnt) {
          float v = acc[m2][n2][r];
          if constexpr (EPI == 1) {
            v = fmaxf(v, 0.f);
            Hout[(size_t)(rowbase + grow) * NDT + col] = (__bf16)(v * v);
          } else {
            atomicAdd(&Yout[(size_t)toksL[rb + r] * NDT + col], v * sclL[rb + r]);
          }
        }
      }
    }
  }
}

// ---------------- aux loss ----------------
__global__ void aux_kernel(const float* __restrict__ psum, const int* __restrict__ fcnt,
                           float* __restrict__ out) {
  float s = 0.f;
  for (int e = 0; e < 8; ++e) s += ((float)fcnt[e] / 8192.f) * (psum[e] / 8192.f);
  *out = 0.08f * s;  // AUX_COEF * E = 0.01 * 8
}

extern "C" void kernel_launch(void* const* d_in, const int* in_sizes, int n_in,
                              void* d_out, int out_size, void* d_ws, size_t ws_size,
                              hipStream_t stream) {
  const float* x      = (const float*)d_in[0];
  const float* rw     = (const float*)d_in[1];
  const float* wfc    = (const float*)d_in[2];
  const float* wproj  = (const float*)d_in[3];
  const float* wsfc   = (const float*)d_in[4];
  const float* wsproj = (const float*)d_in[5];
  float* y = (float*)d_out;

  char* ws = (char*)d_ws;
  size_t off = 0;
  auto alloc = [&](size_t bytes) {
    void* p = ws + off;
    off += (bytes + 1023) & ~(size_t)1023;
    return p;
  };
  __bf16* xbf      = (__bf16*)alloc((size_t)NTOK * DDIM * 2);          // 16 MB
  __bf16* B1       = (__bf16*)alloc((size_t)9 * HDIM * DDIM * 2);      // 26 MB [9][1408][1024]
  __bf16* B2       = (__bf16*)alloc((size_t)9 * DDIM * HDIM * 2);      // 26 MB [9][1024][1408]
  __bf16* H        = (__bf16*)alloc((size_t)NROWS * HDIM * 2);         // 81 MB
  int*    tok_row  = (int*)alloc((size_t)NROWS * 4);
  float*  scale_row= (float*)alloc((size_t)NROWS * 4);
  int2*   e01      = (int2*)alloc((size_t)NTOK * 8);
  float2* p01      = (float2*)alloc((size_t)NTOK * 8);
  int*    counts   = (int*)alloc(1024);
  float*  psum     = (float*)alloc(1024);
  int*    fcnt     = (int*)alloc(1024);
  (void)ws_size; (void)out_size; (void)in_sizes; (void)n_in;

  zero_kernel<<<2048, 256, 0, stream>>>(y, psum, fcnt);
  convx_kernel<<<4096, 256, 0, stream>>>(x, xbf);
  dim3 tb(32, 8);
  tconv_kernel<<<dim3(44, 32, 8), tb, 0, stream>>>(wfc, B1, 1024, 1408);
  tconv_kernel<<<dim3(44, 32, 1), tb, 0, stream>>>(wsfc, B1 + (size_t)8 * HDIM * DDIM, 1024, 1408);
  tconv_kernel<<<dim3(32, 44, 8), tb, 0, stream>>>(wproj, B2, 1408, 1024);
  tconv_kernel<<<dim3(32, 44, 1), tb, 0, stream>>>(wsproj, B2 + (size_t)8 * DDIM * HDIM, 1408, 1024);
  router_kernel<<<256, 256, 0, stream>>>(x, rw, e01, p01, tok_row, scale_row, psum, fcnt);
  dispatch_kernel<<<1, 256, 0, stream>>>(e01, p01, tok_row, scale_row, counts);
  // GEMM1: H = relu(gather(x) @ B1)^2 ; 128x128 tiles: (64 + 8*20) rt * 11 ct = 2464
  gemm_kernel<1024, 1408, true, 1><<<2464, 256, 0, stream>>>(
      xbf, B1, H, nullptr, counts, tok_row, scale_row);
  // GEMM2: y[tok] += scale * (H @ B2) ; 128x128 tiles: 224 rt * 8 ct = 1792
  gemm_kernel<1408, 1024, false, 2><<<1792, 256, 0, stream>>>(
      H, B2, nullptr, y, counts, tok_row, scale_row);
  aux_kernel<<<1, 1, 0, stream>>>(psum, fcnt, y + YN);
}